// Round 5
// baseline (323.918 us; speedup 1.0000x reference)
//
#include <hip/hip_runtime.h>
#include <math.h>

#define EPS 1e-5f

typedef float f32x4 __attribute__((ext_vector_type(4)));

// Problem shapes (fixed for this bench)
constexpr int B   = 2;
constexpr int Ca  = 512;
constexpr int T   = 256;
constexpr int Fa  = 128;
constexpr int Tv  = 64;
constexpr int CHW = T * Fa;          // per-(b,c) audio plane = 32768 floats
constexpr int NSTAT = B * CHW;       // elements per channel for BN stats
constexpr int VID_PER_B = Ca * Tv;   // 32768

// workspace layout (floats):
//  [0..2048)       partial sums  s   (2048 blocks: idx = b*1024 + c*2 + half)
//  [2048..4096)    partial sums  s2
//  [4096..69632)   att  (B*Ca*Tv = 65536)
//  [69632..135168) vr
constexpr int WS_PS   = 0;
constexpr int WS_PS2  = 2048;
constexpr int WS_ATT  = 4096;
constexpr int WS_VR   = WS_ATT + B * VID_PER_B;

// ------------------------------------------------------------------
// Kernel 1 (k_pre): blocks 0..2047  -> per-half-plane audio sum/sumsq
//                   blocks 2048/2049 -> video GN + softmax for b=blk-2048
// Video work rides for free under the BW-bound stats pass.
// ------------------------------------------------------------------
__global__ __launch_bounds__(256) void k_pre(
    const float* __restrict__ audio,
    const float* __restrict__ video,
    const float* __restrict__ aw, const float* __restrict__ ab,
    const float* __restrict__ ag, const float* __restrict__ abeta,
    const float* __restrict__ rw, const float* __restrict__ rb,
    const float* __restrict__ rg, const float* __restrict__ rbeta,
    float* __restrict__ ws)
{
    const int blk = blockIdx.x;
    const int tid = threadIdx.x;
    __shared__ float sh[17];   // stats: [0..4)+[4..8); video: red[4][4]+stats[4]

    if (blk < 2048) {
        // ---- audio partial sums: 4096 contiguous float4 (64 KiB)
        const f32x4* a4 = reinterpret_cast<const f32x4*>(audio) + (size_t)blk * 4096;
        float s = 0.f, s2 = 0.f;
        #pragma unroll
        for (int k = 0; k < 16; ++k) {
            f32x4 v = a4[tid + k * 256];
            s  += v.x + v.y + v.z + v.w;
            s2 += v.x * v.x + v.y * v.y + v.z * v.z + v.w * v.w;
        }
        for (int off = 32; off; off >>= 1) {
            s  += __shfl_xor(s,  off);
            s2 += __shfl_xor(s2, off);
        }
        const int wid = tid >> 6;
        if ((tid & 63) == 0) { sh[wid] = s; sh[4 + wid] = s2; }
        __syncthreads();
        if (tid == 0) {
            ws[WS_PS  + blk] = sh[0] + sh[1] + sh[2] + sh[3];
            ws[WS_PS2 + blk] = sh[4] + sh[5] + sh[6] + sh[7];
        }
        return;
    }

    // ---- video branch for sample b (256 threads: t = tid&63, cl = tid>>6)
    const int b  = blk - 2048;
    const int t  = tid & 63;
    const int cl = tid >> 6;           // 0..3
    const float* vbase = video + (size_t)b * VID_PER_B;
    float* att_out = ws + WS_ATT;
    float* vr_out  = ws + WS_VR;

    float s1a = 0.f, s2a = 0.f, s1r = 0.f, s2r = 0.f;
    #pragma unroll 8
    for (int i = 0; i < Ca / 4; ++i) {
        const int c = cl + 4 * i;
        float v  = vbase[c * Tv + t];
        float xa = v * aw[c] + ab[c];
        float xr = v * rw[c] + rb[c];
        s1a += xa; s2a += xa * xa;
        s1r += xr; s2r += xr * xr;
    }
    for (int off = 32; off; off >>= 1) {
        s1a += __shfl_xor(s1a, off); s2a += __shfl_xor(s2a, off);
        s1r += __shfl_xor(s1r, off); s2r += __shfl_xor(s2r, off);
    }
    const int wid = tid >> 6;
    if ((tid & 63) == 0) {
        sh[wid]      = s1a; sh[4 + wid]  = s2a;
        sh[8 + wid]  = s1r; sh[12 + wid] = s2r;
    }
    __syncthreads();
    if (tid == 0) {
        float S1a = sh[0] + sh[1] + sh[2] + sh[3];
        float S2a = sh[4] + sh[5] + sh[6] + sh[7];
        float S1r = sh[8] + sh[9] + sh[10] + sh[11];
        float S2r = sh[12] + sh[13] + sh[14] + sh[15];
        const float inv = 1.f / (float)VID_PER_B;
        float ma = S1a * inv, va = S2a * inv - ma * ma;
        float mr = S1r * inv, vv = S2r * inv - mr * mr;
        sh[0] = ma; sh[1] = rsqrtf(va + EPS);
        sh[2] = mr; sh[3] = rsqrtf(vv + EPS);
    }
    __syncthreads();
    const float ma = sh[0], rsa = sh[1];
    const float mr = sh[2], rsr = sh[3];

    #pragma unroll 8
    for (int i = 0; i < Ca / 4; ++i) {
        const int c = cl + 4 * i;
        float v  = vbase[c * Tv + t];
        float xa = (v * aw[c] + ab[c] - ma) * rsa * ag[c] + abeta[c];
        float xr = (v * rw[c] + rb[c] - mr) * rsr * rg[c] + rbeta[c];

        // softmax over t: lanes of this wave ARE the 64 t-values of row c
        float m = xa;
        for (int off = 32; off; off >>= 1) m = fmaxf(m, __shfl_xor(m, off));
        float e = expf(xa - m);
        float sum = e;
        for (int off = 32; off; off >>= 1) sum += __shfl_xor(sum, off);

        const size_t idx = (size_t)b * VID_PER_B + (size_t)c * Tv + t;
        att_out[idx] = e / sum;
        vr_out[idx]  = xr;
    }
}

// ------------------------------------------------------------------
// Kernel 2 (k_fuse): fused output. Each block covers 1024 contiguous
// float4 = 1/8 of one (b,c) plane -> c is block-uniform. The block
// derives its own BN affine coefficients from the 4 partials of its
// channel (uniform -> s_loads + a few VALU ops, ~free vs 16 KiB I/O).
// ------------------------------------------------------------------
__global__ __launch_bounds__(256) void k_fuse(
    const float* __restrict__ audio,
    const float* __restrict__ ws,
    const float* __restrict__ vw, const float* __restrict__ vg, const float* __restrict__ vb,
    const float* __restrict__ gw, const float* __restrict__ gg, const float* __restrict__ gb,
    float* __restrict__ out)
{
    const int blk = blockIdx.x;
    const int tid = threadIdx.x;
    const f32x4* a4 = reinterpret_cast<const f32x4*>(audio);
    f32x4*       o4 = reinterpret_cast<f32x4*>(out);

    const size_t bc = (size_t)(blk >> 3);       // b*Ca + c  (8 blocks per plane)
    const int    c  = (int)(bc & (size_t)(Ca - 1));
    const int    t_base = (blk & 7) * 32;       // plane-local t offset

    // per-channel BN coefficients (block-uniform)
    const float* ps  = ws + WS_PS;
    const float* ps2 = ws + WS_PS2;
    const float S  = ps[c * 2]  + ps[c * 2 + 1]  + ps[1024 + c * 2]  + ps[1024 + c * 2 + 1];
    const float S2 = ps2[c * 2] + ps2[c * 2 + 1] + ps2[1024 + c * 2] + ps2[1024 + c * 2 + 1];
    const float inv  = 1.f / (float)NSTAT;
    const float mean = S * inv;
    const float var  = S2 * inv - mean * mean;
    float w  = vw[c];
    const float sv = w * rsqrtf(w * w * var + EPS) * vg[c];
    const float bv = vb[c] - mean * sv;
    w = gw[c];
    const float sg = w * rsqrtf(w * w * var + EPS) * gg[c];
    const float bg = gb[c] - mean * sg;

    const float* att = ws + WS_ATT + bc * Tv;
    const float* vr  = ws + WS_VR  + bc * Tv;

    #pragma unroll
    for (int k = 0; k < 4; ++k) {
        const size_t i = (size_t)blk * 1024 + tid + (size_t)k * 256;
        const int    t = t_base + k * 8 + (tid >> 5);
        const float av = att[t >> 2];
        const float vv = vr[t >> 2];

        f32x4 a = __builtin_nontemporal_load(&a4[i]);
        f32x4 r;
        r.x = av * (a.x * sv + bv) + fmaxf(a.x * sg + bg, 0.f) * vv;
        r.y = av * (a.y * sv + bv) + fmaxf(a.y * sg + bg, 0.f) * vv;
        r.z = av * (a.z * sv + bv) + fmaxf(a.z * sg + bg, 0.f) * vv;
        r.w = av * (a.w * sv + bv) + fmaxf(a.w * sg + bg, 0.f) * vv;
        __builtin_nontemporal_store(r, &o4[i]);
    }
}

// ------------------------------------------------------------------
extern "C" void kernel_launch(void* const* d_in, const int* in_sizes, int n_in,
                              void* d_out, int out_size, void* d_ws, size_t ws_size,
                              hipStream_t stream) {
    const float* audio   = (const float*)d_in[0];
    const float* video   = (const float*)d_in[1];
    const float* value_w = (const float*)d_in[2];
    const float* value_g = (const float*)d_in[3];
    const float* value_b = (const float*)d_in[4];
    const float* gate_w  = (const float*)d_in[5];
    const float* gate_g  = (const float*)d_in[6];
    const float* gate_b  = (const float*)d_in[7];
    const float* att_w   = (const float*)d_in[8];
    const float* att_b   = (const float*)d_in[9];
    const float* att_g   = (const float*)d_in[10];
    const float* att_be  = (const float*)d_in[11];
    const float* res_w   = (const float*)d_in[12];
    const float* res_b   = (const float*)d_in[13];
    const float* res_g   = (const float*)d_in[14];
    const float* res_be  = (const float*)d_in[15];

    float* ws = (float*)d_ws;

    k_pre<<<2050, 256, 0, stream>>>(audio, video,
                                    att_w, att_b, att_g, att_be,
                                    res_w, res_b, res_g, res_be, ws);
    const int blocks = B * Ca * T * Fa / 4 / 1024;   // 8192
    k_fuse<<<blocks, 256, 0, stream>>>(audio, ws,
                                       value_w, value_g, value_b,
                                       gate_w, gate_g, gate_b,
                                       (float*)d_out);
}

// Round 6
// 288.339 us; speedup vs baseline: 1.1234x; 1.1234x over previous
//
#include <hip/hip_runtime.h>
#include <math.h>

#define EPS 1e-5f

typedef float f32x4 __attribute__((ext_vector_type(4)));

// Problem shapes (fixed for this bench)
constexpr int B   = 2;
constexpr int Ca  = 512;
constexpr int T   = 256;
constexpr int Fa  = 128;
constexpr int Tv  = 64;
constexpr int CHW = T * Fa;          // per-(b,c) audio plane = 32768 floats
constexpr int NSTAT = B * CHW;       // elements per channel for BN stats
constexpr int VID_PER_B = Ca * Tv;   // 32768

// workspace layout (floats):
//  [0..2048)     audio partial sums  s   (idx = b*1024 + c*2 + half)
//  [2048..4096)  audio partial sums  s2
//  [4096..4104)  video GN stats: per b {ma, rsa, mr, rsr}
constexpr int WS_PS   = 0;
constexpr int WS_PS2  = 2048;
constexpr int WS_VID  = 4096;

// ------------------------------------------------------------------
// Kernel 1 (k_pre):
//   blocks 0..2047   -> per-half-plane audio sum/sumsq (64 KiB each)
//   blocks 2048/2049 -> video GN partial stats for b = blk-2048
// Video stats are 4 accumulators + ONE reduction -> ~3 us, hides
// under the audio drain (dispatched last).
// ------------------------------------------------------------------
__global__ __launch_bounds__(256) void k_pre(
    const float* __restrict__ audio,
    const float* __restrict__ video,
    const float* __restrict__ aw, const float* __restrict__ ab,
    const float* __restrict__ rw, const float* __restrict__ rb,
    float* __restrict__ ws)
{
    const int blk = blockIdx.x;
    const int tid = threadIdx.x;
    __shared__ float sh[16];

    if (blk < 2048) {
        // ---- audio partial sums: 4096 contiguous float4 (64 KiB)
        const f32x4* a4 = reinterpret_cast<const f32x4*>(audio) + (size_t)blk * 4096;
        float s = 0.f, s2 = 0.f;
        #pragma unroll
        for (int k = 0; k < 16; ++k) {
            f32x4 v = a4[tid + k * 256];
            s  += v.x + v.y + v.z + v.w;
            s2 += v.x * v.x + v.y * v.y + v.z * v.z + v.w * v.w;
        }
        for (int off = 32; off; off >>= 1) {
            s  += __shfl_xor(s,  off);
            s2 += __shfl_xor(s2, off);
        }
        const int wid = tid >> 6;
        if ((tid & 63) == 0) { sh[wid] = s; sh[4 + wid] = s2; }
        __syncthreads();
        if (tid == 0) {
            ws[WS_PS  + blk] = sh[0] + sh[1] + sh[2] + sh[3];
            ws[WS_PS2 + blk] = sh[4] + sh[5] + sh[6] + sh[7];
        }
        return;
    }

    // ---- video GN partial stats for sample b (8192 float4 total)
    const int b = blk - 2048;
    const f32x4* v4 = reinterpret_cast<const f32x4*>(video) + (size_t)b * (VID_PER_B / 4);

    float s1a = 0.f, s2a = 0.f, s1r = 0.f, s2r = 0.f;
    #pragma unroll 8
    for (int j = 0; j < VID_PER_B / 4 / 256; ++j) {      // 32 iters
        const int q = tid + j * 256;                     // f4 index
        const int c = q >> 4;                            // 16 f4 per c-row
        const float wa = aw[c], ba = ab[c];
        const float wr = rw[c], br = rb[c];
        f32x4 v = v4[q];
        #pragma unroll
        for (int e = 0; e < 4; ++e) {
            float xa = v[e] * wa + ba;
            float xr = v[e] * wr + br;
            s1a += xa; s2a += xa * xa;
            s1r += xr; s2r += xr * xr;
        }
    }
    for (int off = 32; off; off >>= 1) {
        s1a += __shfl_xor(s1a, off); s2a += __shfl_xor(s2a, off);
        s1r += __shfl_xor(s1r, off); s2r += __shfl_xor(s2r, off);
    }
    const int wid = tid >> 6;
    if ((tid & 63) == 0) {
        sh[wid]      = s1a; sh[4 + wid]  = s2a;
        sh[8 + wid]  = s1r; sh[12 + wid] = s2r;
    }
    __syncthreads();
    if (tid == 0) {
        float S1a = sh[0] + sh[1] + sh[2] + sh[3];
        float S2a = sh[4] + sh[5] + sh[6] + sh[7];
        float S1r = sh[8] + sh[9] + sh[10] + sh[11];
        float S2r = sh[12] + sh[13] + sh[14] + sh[15];
        const float inv = 1.f / (float)VID_PER_B;
        float ma = S1a * inv, va = S2a * inv - ma * ma;
        float mr = S1r * inv, vv = S2r * inv - mr * mr;
        ws[WS_VID + b * 4 + 0] = ma;
        ws[WS_VID + b * 4 + 1] = rsqrtf(va + EPS);
        ws[WS_VID + b * 4 + 2] = mr;
        ws[WS_VID + b * 4 + 3] = rsqrtf(vv + EPS);
    }
}

// ------------------------------------------------------------------
// Kernel 2 (k_fuse): each block covers 1024 contiguous float4 = 1/8
// of one (b,c) plane. The block derives its channel's BN affine from
// the audio partials (block-uniform scalars), and wave 0 computes the
// channel's att/vr row inline (64-lane softmax = ONE shuffle
// reduction) into LDS. Then streams 16 KiB with nt stores.
// ------------------------------------------------------------------
__global__ __launch_bounds__(256) void k_fuse(
    const float* __restrict__ audio,
    const float* __restrict__ video,
    const float* __restrict__ ws,
    const float* __restrict__ vw, const float* __restrict__ vg, const float* __restrict__ vb,
    const float* __restrict__ gw, const float* __restrict__ gg, const float* __restrict__ gb,
    const float* __restrict__ aw, const float* __restrict__ ab,
    const float* __restrict__ ag, const float* __restrict__ abeta,
    const float* __restrict__ rw, const float* __restrict__ rb,
    const float* __restrict__ rg, const float* __restrict__ rbeta,
    float* __restrict__ out)
{
    const int blk = blockIdx.x;
    const int tid = threadIdx.x;
    const f32x4* a4 = reinterpret_cast<const f32x4*>(audio);
    f32x4*       o4 = reinterpret_cast<f32x4*>(out);
    __shared__ float sm_att[Tv];
    __shared__ float sm_vr[Tv];

    const size_t bc = (size_t)(blk >> 3);       // b*Ca + c  (8 blocks per plane)
    const int    c  = (int)(bc & (size_t)(Ca - 1));
    const int    b  = (int)(bc >> 9);           // Ca = 512
    const int    t_base = (blk & 7) * 32;       // plane-local t offset

    // ---- per-channel BN coefficients (block-uniform)
    const float* ps  = ws + WS_PS;
    const float* ps2 = ws + WS_PS2;
    const float S  = ps[c * 2]  + ps[c * 2 + 1]  + ps[1024 + c * 2]  + ps[1024 + c * 2 + 1];
    const float S2 = ps2[c * 2] + ps2[c * 2 + 1] + ps2[1024 + c * 2] + ps2[1024 + c * 2 + 1];
    const float inv  = 1.f / (float)NSTAT;
    const float mean = S * inv;
    const float var  = S2 * inv - mean * mean;
    float w  = vw[c];
    const float sv = w * rsqrtf(w * w * var + EPS) * vg[c];
    const float bv = vb[c] - mean * sv;
    w = gw[c];
    const float sg = w * rsqrtf(w * w * var + EPS) * gg[c];
    const float bg = gb[c] - mean * sg;

    // ---- wave 0: this channel's att (GN+softmax) and vr (GN) row
    if (tid < 64) {
        const int t = tid;                       // video time index
        const float ma  = ws[WS_VID + b * 4 + 0];
        const float rsa = ws[WS_VID + b * 4 + 1];
        const float mr  = ws[WS_VID + b * 4 + 2];
        const float rsr = ws[WS_VID + b * 4 + 3];
        const float v = video[(size_t)b * VID_PER_B + (size_t)c * Tv + t];
        const float xa = (v * aw[c] + ab[c] - ma) * rsa * ag[c] + abeta[c];
        const float xr = (v * rw[c] + rb[c] - mr) * rsr * rg[c] + rbeta[c];

        float m = xa;
        for (int off = 32; off; off >>= 1) m = fmaxf(m, __shfl_xor(m, off));
        float e = expf(xa - m);
        float sum = e;
        for (int off = 32; off; off >>= 1) sum += __shfl_xor(sum, off);
        sm_att[t] = e / sum;
        sm_vr[t]  = xr;
    }
    __syncthreads();

    // ---- stream 16 KiB: out = att*(a*sv+bv) + relu(a*sg+bg)*vr
    #pragma unroll
    for (int k = 0; k < 4; ++k) {
        const size_t i = (size_t)blk * 1024 + tid + (size_t)k * 256;
        const int    t = t_base + k * 8 + (tid >> 5);
        const float av = sm_att[t >> 2];
        const float vv = sm_vr[t >> 2];

        f32x4 a = a4[i];
        f32x4 r;
        r.x = av * (a.x * sv + bv) + fmaxf(a.x * sg + bg, 0.f) * vv;
        r.y = av * (a.y * sv + bv) + fmaxf(a.y * sg + bg, 0.f) * vv;
        r.z = av * (a.z * sv + bv) + fmaxf(a.z * sg + bg, 0.f) * vv;
        r.w = av * (a.w * sv + bv) + fmaxf(a.w * sg + bg, 0.f) * vv;
        __builtin_nontemporal_store(r, &o4[i]);
    }
}

// ------------------------------------------------------------------
extern "C" void kernel_launch(void* const* d_in, const int* in_sizes, int n_in,
                              void* d_out, int out_size, void* d_ws, size_t ws_size,
                              hipStream_t stream) {
    const float* audio   = (const float*)d_in[0];
    const float* video   = (const float*)d_in[1];
    const float* value_w = (const float*)d_in[2];
    const float* value_g = (const float*)d_in[3];
    const float* value_b = (const float*)d_in[4];
    const float* gate_w  = (const float*)d_in[5];
    const float* gate_g  = (const float*)d_in[6];
    const float* gate_b  = (const float*)d_in[7];
    const float* att_w   = (const float*)d_in[8];
    const float* att_b   = (const float*)d_in[9];
    const float* att_g   = (const float*)d_in[10];
    const float* att_be  = (const float*)d_in[11];
    const float* res_w   = (const float*)d_in[12];
    const float* res_b   = (const float*)d_in[13];
    const float* res_g   = (const float*)d_in[14];
    const float* res_be  = (const float*)d_in[15];

    float* ws = (float*)d_ws;

    k_pre<<<2050, 256, 0, stream>>>(audio, video, att_w, att_b, res_w, res_b, ws);
    const int blocks = B * Ca * T * Fa / 4 / 1024;   // 8192
    k_fuse<<<blocks, 256, 0, stream>>>(audio, video, ws,
                                       value_w, value_g, value_b,
                                       gate_w, gate_g, gate_b,
                                       att_w, att_b, att_g, att_be,
                                       res_w, res_b, res_g, res_be,
                                       (float*)d_out);
}